// Round 4
// baseline (810.604 us; speedup 1.0000x reference)
//
#include <hip/hip_runtime.h>
#include <math.h>

// ---- problem constants (static per reference) ----
#define D_MODEL   256
#define N_HEADS   8
#define HEAD_DIM  32
#define N_LEVELS  3
#define N_POINTS  2
#define BS        16
#define NQ        900
#define LEN_IN    13125
#define M_Q       (BS * NQ * N_LEVELS)   // 43200
#define M_V       (BS * LEN_IN)          // 210000
#define NCAT      144                    // 96 offset cols + 48 attn cols
#define NCATP     192                    // padded to 3 wave-col-groups of 64

typedef _Float16 f16x8 __attribute__((ext_vector_type(8)));
typedef _Float16 f16x4 __attribute__((ext_vector_type(4)));
typedef float f32x4 __attribute__((ext_vector_type(4)));

// ---------------------------------------------------------------------------
// Weight prep: W[K=256][N] fp32 -> Wt_hi[n][k], Wt_lo[n][k] fp16 split.
// ---------------------------------------------------------------------------
__global__ __launch_bounds__(256) void convert_weight_kernel(
    const float* __restrict__ W, _Float16* __restrict__ Wth,
    _Float16* __restrict__ Wtl, int N, int Npad) {
  const int idx = blockIdx.x * 256 + threadIdx.x;
  if (idx >= Npad * 256) return;
  const int n = idx >> 8;
  const int k = idx & 255;
  const float v = (n < N) ? W[(size_t)k * N + n] : 0.0f;
  const _Float16 h = (_Float16)v;
  Wth[idx] = h;
  Wtl[idx] = (_Float16)(v - (float)h);
}

// concat [W_off | W_attn] -> transposed split, n-padded to NCATP; bias concat.
__global__ __launch_bounds__(256) void convert_cat_kernel(
    const float* __restrict__ Woff, const float* __restrict__ Wattn,
    const float* __restrict__ boff, const float* __restrict__ battn,
    _Float16* __restrict__ Wth, _Float16* __restrict__ Wtl,
    float* __restrict__ bcat) {
  const int idx = blockIdx.x * 256 + threadIdx.x;
  if (idx >= NCATP * 256) return;
  const int n = idx >> 8;
  const int k = idx & 255;
  float v = 0.0f;
  if (n < 96) v = Woff[(size_t)k * 96 + n];
  else if (n < NCAT) v = Wattn[(size_t)k * 48 + (n - 96)];
  const _Float16 h = (_Float16)v;
  Wth[idx] = h;
  Wtl[idx] = (_Float16)(v - (float)h);
  if (idx < NCAT) bcat[idx] = (idx < 96) ? boff[idx] : battn[idx - 96];
}

// ---------------------------------------------------------------------------
// C[M,N] = A[M,256] @ W[256,N] + bias via fp16x3 split MFMA.
// Structure (T14 async-split, one barrier per K-step):
//   - A tile (64 x 32) double-buffered in LDS, global->reg prefetch 1 step
//     ahead, fp32->fp16 hi/lo split during the reg->LDS stage.
//   - B fragments loaded DIRECTLY global->reg (weight is 256KB, L2-hot),
//     prefetched 1 K-step ahead. No B in LDS.
// 256 threads = 4 waves side-by-side in N; wave tile 64 x (FC*16).
// Fragment mapping verified end-to-end in round 3 (passed):
//   A/B frag: lane&15 -> row/col, (lane>>4)*8+j -> k.
//   C/D:      col = lane&15, row = (lane>>4)*4 + reg.
// ---------------------------------------------------------------------------
template <int FC>
__global__ __launch_bounds__(256) void gemm2_kernel(
    const float* __restrict__ A, const _Float16* __restrict__ Bth,
    const _Float16* __restrict__ Btl, const float* __restrict__ bias,
    float* __restrict__ C, int M, int N) {
  constexpr int K = 256;
  constexpr int LDA = 40;  // halfs; 80B rows -> 16B-aligned b128, ~2-way banks
  __shared__ _Float16 Ah[2][64][LDA];
  __shared__ _Float16 Al[2][64][LDA];

  const int tid = threadIdx.x;
  const int wid = tid >> 6;
  const int lane = tid & 63;
  const int bm = blockIdx.x * 64;
  const int rsel = lane & 15;
  const int khi = (lane >> 4) * 8;

  // A staging map: 8 lanes x 4 floats = one 32-float k-row chunk; 32 rows x2
  const int arow = tid >> 3;        // 0..31
  const int ak = (tid & 7) * 4;     // 0,4,...,28
  const bool g0 = (bm + arow) < M;
  const bool g1 = (bm + arow + 32) < M;
  const float* ap0 = A + (size_t)(bm + arow) * K + ak;
  const float* ap1 = ap0 + (size_t)32 * K;

  const _Float16* bhp = Bth + (size_t)(wid * FC * 16 + rsel) * K + khi;
  const _Float16* blp = Btl + (size_t)(wid * FC * 16 + rsel) * K + khi;

  f32x4 acc[4][FC];
#pragma unroll
  for (int fr = 0; fr < 4; ++fr)
#pragma unroll
    for (int fc = 0; fc < FC; ++fc) acc[fr][fc] = (f32x4)0.0f;

  const float4 z4 = make_float4(0.f, 0.f, 0.f, 0.f);

  // ---- prologue: prefetch step 0 ----
  float4 a0 = g0 ? *reinterpret_cast<const float4*>(ap0) : z4;
  float4 a1 = g1 ? *reinterpret_cast<const float4*>(ap1) : z4;
  f16x8 bh[FC], bl[FC];
#pragma unroll
  for (int fc = 0; fc < FC; ++fc) {
    bh[fc] = *reinterpret_cast<const f16x8*>(bhp + (size_t)fc * 16 * K);
    bl[fc] = *reinterpret_cast<const f16x8*>(blp + (size_t)fc * 16 * K);
  }
  {
    f16x4 h0, l0, h1, l1;
    h0[0] = (_Float16)a0.x; l0[0] = (_Float16)(a0.x - (float)h0[0]);
    h0[1] = (_Float16)a0.y; l0[1] = (_Float16)(a0.y - (float)h0[1]);
    h0[2] = (_Float16)a0.z; l0[2] = (_Float16)(a0.z - (float)h0[2]);
    h0[3] = (_Float16)a0.w; l0[3] = (_Float16)(a0.w - (float)h0[3]);
    h1[0] = (_Float16)a1.x; l1[0] = (_Float16)(a1.x - (float)h1[0]);
    h1[1] = (_Float16)a1.y; l1[1] = (_Float16)(a1.y - (float)h1[1]);
    h1[2] = (_Float16)a1.z; l1[2] = (_Float16)(a1.z - (float)h1[2]);
    h1[3] = (_Float16)a1.w; l1[3] = (_Float16)(a1.w - (float)h1[3]);
    *reinterpret_cast<f16x4*>(&Ah[0][arow][ak]) = h0;
    *reinterpret_cast<f16x4*>(&Al[0][arow][ak]) = l0;
    *reinterpret_cast<f16x4*>(&Ah[0][arow + 32][ak]) = h1;
    *reinterpret_cast<f16x4*>(&Al[0][arow + 32][ak]) = l1;
  }
  __syncthreads();

#pragma unroll 2
  for (int s = 0; s < 8; ++s) {
    const int cur = s & 1;
    // ---- issue next-step loads early (hide under MFMA) ----
    float4 na0 = z4, na1 = z4;
    f16x8 nbh[FC], nbl[FC];
    if (s < 7) {
      na0 = g0 ? *reinterpret_cast<const float4*>(ap0 + (s + 1) * 32) : z4;
      na1 = g1 ? *reinterpret_cast<const float4*>(ap1 + (s + 1) * 32) : z4;
#pragma unroll
      for (int fc = 0; fc < FC; ++fc) {
        nbh[fc] = *reinterpret_cast<const f16x8*>(
            bhp + (size_t)fc * 16 * K + (s + 1) * 32);
        nbl[fc] = *reinterpret_cast<const f16x8*>(
            blp + (size_t)fc * 16 * K + (s + 1) * 32);
      }
    }
    // ---- A fragments from LDS ----
    f16x8 afh[4], afl[4];
#pragma unroll
    for (int fr = 0; fr < 4; ++fr) {
      afh[fr] = *reinterpret_cast<const f16x8*>(&Ah[cur][fr * 16 + rsel][khi]);
      afl[fr] = *reinterpret_cast<const f16x8*>(&Al[cur][fr * 16 + rsel][khi]);
    }
    // ---- 3-term split MFMA ----
#pragma unroll
    for (int fr = 0; fr < 4; ++fr)
#pragma unroll
      for (int fc = 0; fc < FC; ++fc) {
        acc[fr][fc] = __builtin_amdgcn_mfma_f32_16x16x32_f16(
            afh[fr], bh[fc], acc[fr][fc], 0, 0, 0);
        acc[fr][fc] = __builtin_amdgcn_mfma_f32_16x16x32_f16(
            afh[fr], bl[fc], acc[fr][fc], 0, 0, 0);
        acc[fr][fc] = __builtin_amdgcn_mfma_f32_16x16x32_f16(
            afl[fr], bh[fc], acc[fr][fc], 0, 0, 0);
      }
    // ---- stage next A tile (vmcnt wait lands here), rotate B regs ----
    if (s < 7) {
      const int nxt = cur ^ 1;
      f16x4 h0, l0, h1, l1;
      h0[0] = (_Float16)na0.x; l0[0] = (_Float16)(na0.x - (float)h0[0]);
      h0[1] = (_Float16)na0.y; l0[1] = (_Float16)(na0.y - (float)h0[1]);
      h0[2] = (_Float16)na0.z; l0[2] = (_Float16)(na0.z - (float)h0[2]);
      h0[3] = (_Float16)na0.w; l0[3] = (_Float16)(na0.w - (float)h0[3]);
      h1[0] = (_Float16)na1.x; l1[0] = (_Float16)(na1.x - (float)h1[0]);
      h1[1] = (_Float16)na1.y; l1[1] = (_Float16)(na1.y - (float)h1[1]);
      h1[2] = (_Float16)na1.z; l1[2] = (_Float16)(na1.z - (float)h1[2]);
      h1[3] = (_Float16)na1.w; l1[3] = (_Float16)(na1.w - (float)h1[3]);
      *reinterpret_cast<f16x4*>(&Ah[nxt][arow][ak]) = h0;
      *reinterpret_cast<f16x4*>(&Al[nxt][arow][ak]) = l0;
      *reinterpret_cast<f16x4*>(&Ah[nxt][arow + 32][ak]) = h1;
      *reinterpret_cast<f16x4*>(&Al[nxt][arow + 32][ak]) = l1;
#pragma unroll
      for (int fc = 0; fc < FC; ++fc) { bh[fc] = nbh[fc]; bl[fc] = nbl[fc]; }
      __syncthreads();
    }
  }

  // ---- store with bias ----
  float bs_[FC];
#pragma unroll
  for (int fc = 0; fc < FC; ++fc) {
    const int col = wid * FC * 16 + fc * 16 + rsel;
    bs_[fc] = (col < N) ? bias[col] : 0.0f;
  }
#pragma unroll
  for (int fr = 0; fr < 4; ++fr)
#pragma unroll
    for (int i = 0; i < 4; ++i) {
      const int row = bm + fr * 16 + (lane >> 4) * 4 + i;
      if (row >= M) continue;
#pragma unroll
      for (int fc = 0; fc < FC; ++fc) {
        const int col = wid * FC * 16 + fc * 16 + rsel;
        if (col < N) C[(size_t)row * N + col] = acc[fr][fc][i] + bs_[fc];
      }
    }
}

// ---------------------------------------------------------------------------
// Fused softmax + bilinear sampling + attention-weighted accumulation.
// One block per (b, q, fl) row; 256 threads = 8 heads x 32 dims.
// offs_attn: [M_Q, 144]  cols 0..95 offsets (h*12 + (l*2+p)*2 + c),
//                        cols 96..143 attn logits (96 + h*6 + l*2 + p)
// ---------------------------------------------------------------------------
__global__ __launch_bounds__(256) void sample_kernel(
    const float* __restrict__ value, const float* __restrict__ refpts,
    const float* __restrict__ offs_attn, float* __restrict__ out_mid) {
  const int row = blockIdx.x;            // b*2700 + q*3 + fl
  const int tid = threadIdx.x;
  const int h = tid >> 5;
  const int d = tid & 31;
  const int b = row / (NQ * N_LEVELS);

  const int LVL_W[3] = {100, 50, 25};
  const int LVL_H[3] = {100, 50, 25};
  const int LVL_BASE[3] = {0, 10000, 12500};

  const float* off_p  = offs_attn + (size_t)row * NCAT + h * 12;
  const float* attn_p = offs_attn + (size_t)row * NCAT + 96 + h * 6;

  float aw[6];
  float mx = -INFINITY;
#pragma unroll
  for (int j = 0; j < 6; ++j) {
    aw[j] = attn_p[j];
    mx = fmaxf(mx, aw[j]);
  }
  float ssum = 0.f;
#pragma unroll
  for (int j = 0; j < 6; ++j) {
    aw[j] = expf(aw[j] - mx);
    ssum += aw[j];
  }
  const float rs = 1.0f / ssum;

  const float rx = refpts[(size_t)row * 2 + 0];
  const float ry = refpts[(size_t)row * 2 + 1];

  const float* vbase = value + (size_t)b * LEN_IN * 256 + h * 32 + d;
  float acc = 0.f;

#pragma unroll
  for (int l = 0; l < N_LEVELS; ++l) {
    const int W = LVL_W[l], base = LVL_BASE[l];
    const float fW = (float)LVL_W[l], fH = (float)LVL_H[l];
#pragma unroll
    for (int p = 0; p < N_POINTS; ++p) {
      const float ox = off_p[(l * 2 + p) * 2 + 0];
      const float oy = off_p[(l * 2 + p) * 2 + 1];
      const float x = (rx + ox / fW) * fW - 0.5f;
      const float y = (ry + oy / fH) * fH - 0.5f;
      const float x0 = floorf(x);
      const float y0 = floorf(y);
      const float wa = aw[l * 2 + p] * rs;
#pragma unroll
      for (int dy = 0; dy < 2; ++dy) {
#pragma unroll
        for (int dx = 0; dx < 2; ++dx) {
          const float xi = x0 + (float)dx;
          const float yi = y0 + (float)dy;
          const float wgt = (1.0f - fabsf(x - xi)) * (1.0f - fabsf(y - yi));
          const bool valid = (xi >= 0.f) && (xi <= fW - 1.f) &&
                             (yi >= 0.f) && (yi <= fH - 1.f);
          const int xic = (int)fminf(fmaxf(xi, 0.f), fW - 1.f);
          const int yic = (int)fminf(fmaxf(yi, 0.f), fH - 1.f);
          const int pos = base + yic * W + xic;
          const float g = vbase[(size_t)pos * 256];
          acc = fmaf(g, valid ? wgt * wa : 0.0f, acc);
        }
      }
    }
  }
  out_mid[(size_t)row * 256 + tid] = acc;
}

// ---------------------------------------------------------------------------
extern "C" void kernel_launch(void* const* d_in, const int* in_sizes, int n_in,
                              void* d_out, int out_size, void* d_ws,
                              size_t ws_size, hipStream_t stream) {
  const float* query   = (const float*)d_in[0];   // [16,900,3,256]
  const float* refpts  = (const float*)d_in[1];   // [16,900,3,2]
  const float* in_flat = (const float*)d_in[2];   // [16,13125,256]
  // d_in[3]: spatial shapes (static, hardcoded)
  const float* W_value = (const float*)d_in[4];
  const float* b_value = (const float*)d_in[5];
  const float* W_off   = (const float*)d_in[6];
  const float* b_off   = (const float*)d_in[7];
  const float* W_attn  = (const float*)d_in[8];
  const float* b_attn  = (const float*)d_in[9];
  const float* W_out   = (const float*)d_in[10];
  const float* b_out   = (const float*)d_in[11];
  float* out = (float*)d_out;

  char* ws = (char*)d_ws;
  float* value     = (float*)ws; ws += (size_t)M_V * 256 * sizeof(float);
  float* out_mid   = (float*)ws; ws += (size_t)M_Q * 256 * sizeof(float);
  float* offs_attn = (float*)ws; ws += (size_t)M_Q * NCAT * sizeof(float);
  _Float16* Wvh = (_Float16*)ws; ws += 256 * 256 * sizeof(_Float16);
  _Float16* Wvl = (_Float16*)ws; ws += 256 * 256 * sizeof(_Float16);
  _Float16* Woh = (_Float16*)ws; ws += 256 * 256 * sizeof(_Float16);
  _Float16* Wol = (_Float16*)ws; ws += 256 * 256 * sizeof(_Float16);
  _Float16* Wch = (_Float16*)ws; ws += NCATP * 256 * sizeof(_Float16);
  _Float16* Wcl = (_Float16*)ws; ws += NCATP * 256 * sizeof(_Float16);
  float* bcat   = (float*)ws;    ws += 256 * sizeof(float);

  const dim3 blk(256);

  // ---- weight prep (tiny) ----
  convert_weight_kernel<<<dim3(256), blk, 0, stream>>>(W_value, Wvh, Wvl, 256, 256);
  convert_weight_kernel<<<dim3(256), blk, 0, stream>>>(W_out,   Woh, Wol, 256, 256);
  convert_cat_kernel<<<dim3(NCATP), blk, 0, stream>>>(W_off, W_attn, b_off, b_attn,
                                                      Wch, Wcl, bcat);

  // 1) value = input_flatten @ W_value + b_value   (210000 x 256 x 256)
  gemm2_kernel<4><<<dim3((M_V + 63) / 64), blk, 0, stream>>>(
      in_flat, Wvh, Wvl, b_value, value, M_V, 256);

  // 2) [offsets | attn logits] = query @ Wcat + bcat   (43200 x 144 x 256)
  gemm2_kernel<3><<<dim3((M_Q + 63) / 64), blk, 0, stream>>>(
      query, Wch, Wcl, bcat, offs_attn, M_Q, NCAT);

  // 3) softmax + bilinear sampling + weighted sum -> out_mid
  sample_kernel<<<dim3(M_Q), blk, 0, stream>>>(value, refpts, offs_attn,
                                               out_mid);

  // 4) out = out_mid @ W_out + b_out   (43200 x 256 x 256)
  gemm2_kernel<4><<<dim3((M_Q + 63) / 64), blk, 0, stream>>>(
      out_mid, Woh, Wol, b_out, out, M_Q, 256);
}